// Round 2
// baseline (2205.555 us; speedup 1.0000x reference)
//
#include <hip/hip_runtime.h>
#include <hip/hip_bf16.h>
#include <cstddef>

typedef __bf16 bf16_t;
typedef __bf16 bf16x8 __attribute__((ext_vector_type(8)));
typedef __bf16 bf16x4 __attribute__((ext_vector_type(4)));
typedef float f32x4 __attribute__((ext_vector_type(4)));

#define T_LEN 96
#define BATCH 64
#define DM 1024
#define NTB 6144  // T*B

// ---------------- LN2 stats: per (tensor i, batch b) mean & inv-std over T*DM ----------------
__global__ __launch_bounds__(256) void ln_stats_kernel(
    const float* __restrict__ r1, const float* __restrict__ r2,
    const float* __restrict__ r3, const float* __restrict__ r4,
    float* __restrict__ stats)  // [4*64][2]
{
    const int i = blockIdx.x >> 6, b = blockIdx.x & 63;
    const float* r = (i == 0) ? r1 : (i == 1) ? r2 : (i == 2) ? r3 : r4;
    float s = 0.f, ss = 0.f;
    for (int t = 0; t < T_LEN; ++t) {
        float4 v = ((const float4*)(r + (size_t)(t * BATCH + b) * DM))[threadIdx.x];
        s  += v.x + v.y + v.z + v.w;
        ss += v.x * v.x + v.y * v.y + v.z * v.z + v.w * v.w;
    }
    __shared__ float sh[512];
    sh[threadIdx.x] = s; sh[256 + threadIdx.x] = ss;
    __syncthreads();
    for (int off = 128; off > 0; off >>= 1) {
        if (threadIdx.x < off) {
            sh[threadIdx.x] += sh[threadIdx.x + off];
            sh[256 + threadIdx.x] += sh[256 + threadIdx.x + off];
        }
        __syncthreads();
    }
    if (threadIdx.x == 0) {
        const float inv = 1.0f / (float)(T_LEN * DM);
        float mean = sh[0] * inv;
        float var  = sh[256] * inv - mean * mean;
        stats[blockIdx.x * 2 + 0] = mean;
        stats[blockIdx.x * 2 + 1] = rsqrtf(var + 1e-5f);
    }
}

// ---------------- U = mean of 4 normalized tensors, written as bf16 [NTB,1024] ----------------
__global__ __launch_bounds__(256) void compute_u_kernel(
    const float* __restrict__ r1, const float* __restrict__ r2,
    const float* __restrict__ r3, const float* __restrict__ r4,
    const float* __restrict__ stats, bf16_t* __restrict__ U)
{
    const int idx4 = blockIdx.x * 256 + threadIdx.x;   // over NTB*1024/4
    const int b = (idx4 >> 8) & 63;
    const float m0 = stats[(0 * 64 + b) * 2], s0 = stats[(0 * 64 + b) * 2 + 1];
    const float m1 = stats[(1 * 64 + b) * 2], s1 = stats[(1 * 64 + b) * 2 + 1];
    const float m2 = stats[(2 * 64 + b) * 2], s2 = stats[(2 * 64 + b) * 2 + 1];
    const float m3 = stats[(3 * 64 + b) * 2], s3 = stats[(3 * 64 + b) * 2 + 1];
    float4 a = ((const float4*)r1)[idx4];
    float4 c = ((const float4*)r2)[idx4];
    float4 d = ((const float4*)r3)[idx4];
    float4 e = ((const float4*)r4)[idx4];
    bf16x4 o;
    o[0] = (bf16_t)(0.25f * ((a.x - m0) * s0 + (c.x - m1) * s1 + (d.x - m2) * s2 + (e.x - m3) * s3));
    o[1] = (bf16_t)(0.25f * ((a.y - m0) * s0 + (c.y - m1) * s1 + (d.y - m2) * s2 + (e.y - m3) * s3));
    o[2] = (bf16_t)(0.25f * ((a.z - m0) * s0 + (c.z - m1) * s1 + (d.z - m2) * s2 + (e.z - m3) * s3));
    o[3] = (bf16_t)(0.25f * ((a.w - m0) * s0 + (c.w - m1) * s1 + (d.w - m2) * s2 + (e.w - m3) * s3));
    ((bf16x4*)U)[idx4] = o;
}

// ---------------- f32 -> bf16 cast with optional K padding ----------------
__global__ __launch_bounds__(256) void cast_pad_kernel(
    const float* __restrict__ src, bf16_t* __restrict__ dst,
    int rows, int K, int Kpad)
{
    int idx = blockIdx.x * 256 + threadIdx.x;
    if (idx >= rows * Kpad) return;
    int r = idx / Kpad;
    int k = idx - r * Kpad;
    float v = (k < K) ? src[(size_t)r * K + k] : 0.f;
    dst[idx] = (bf16_t)v;
}

// ---------------- Whh fp32 [1024][256] -> MFMA frag-lane-major pack ----------------
// layout: [w(4)][id(128)][lane(64)][e(8)] bf16, id = kq*16 + fi, fi = gt*4 + jf.
// value = Whh[gt*256 + w*64 + jf*16 + (lane&15)][kq*32 + (lane>>4)*8 + e]
__global__ __launch_bounds__(256) void wpk_pack_kernel(
    const float* __restrict__ whh, bf16_t* __restrict__ dst)
{
    int i = blockIdx.x * 256 + threadIdx.x;   // 4*128*64*8 = 262144
    int e = i & 7, lane = (i >> 3) & 63, id = (i >> 9) & 127, w = i >> 16;
    int kq = id >> 4, fi = id & 15, gt = fi >> 2, jf = fi & 3;
    int nrow = gt * 256 + w * 64 + jf * 16 + (lane & 15);
    int k = kq * 32 + (lane >> 4) * 8 + e;
    dst[i] = (bf16_t)whh[nrow * 256 + k];
}

// ---------------- bf16 MFMA GEMM: C[M,N] = A[M,K] @ W[N,K]^T + bias ----------------
// mode 0: outB bf16 row-major ldo.  mode 1: outF fp32, rows permuted (b*96+t), ldo.
// mode 2: outF fp32 in xg2 lane-major layout for lstm_batch_kernel:
//         [bg(4)][t(96)][w(4)][fi(16)*256 + lane(64)*4 + rr(4)] f32
#define GLDP 40  // LDS row pitch in bf16 (32 + 8 pad)
__global__ __launch_bounds__(256) void gemm_bt_kernel(
    const bf16_t* __restrict__ A, const bf16_t* __restrict__ W,
    const float* __restrict__ bias0, const float* __restrict__ bias1,
    int K, float* __restrict__ outF, bf16_t* __restrict__ outB,
    int ldo, int mode)
{
    __shared__ bf16_t As[128 * GLDP];
    __shared__ bf16_t Bs[128 * GLDP];
    const int tid = threadIdx.x;
    const int lane = tid & 63;
    const int wid = tid >> 6;
    const int q = lane >> 4, l15 = lane & 15;
    const int wr = (wid >> 1) * 64, wc = (wid & 1) * 64;
    const size_t br = (size_t)blockIdx.y * 128;
    const size_t bc = (size_t)blockIdx.x * 128;

    const int r0 = tid >> 2;
    const int r1 = r0 + 64;
    const int k0 = (tid & 3) * 8;

    f32x4 acc[4][4] = {};

    for (int kt = 0; kt < K; kt += 32) {
        bf16x8 a0 = *(const bf16x8*)(A + (br + r0) * K + kt + k0);
        bf16x8 a1 = *(const bf16x8*)(A + (br + r1) * K + kt + k0);
        bf16x8 w0 = *(const bf16x8*)(W + (bc + r0) * K + kt + k0);
        bf16x8 w1 = *(const bf16x8*)(W + (bc + r1) * K + kt + k0);
        if (kt) __syncthreads();
        *(bf16x8*)(As + r0 * GLDP + k0) = a0;
        *(bf16x8*)(As + r1 * GLDP + k0) = a1;
        *(bf16x8*)(Bs + r0 * GLDP + k0) = w0;
        *(bf16x8*)(Bs + r1 * GLDP + k0) = w1;
        __syncthreads();
        bf16x8 bfr[4];
        #pragma unroll
        for (int j = 0; j < 4; ++j)
            bfr[j] = *(const bf16x8*)(Bs + (wc + j * 16 + l15) * GLDP + q * 8);
        #pragma unroll
        for (int i = 0; i < 4; ++i) {
            bf16x8 afr = *(const bf16x8*)(As + (wr + i * 16 + l15) * GLDP + q * 8);
            #pragma unroll
            for (int j = 0; j < 4; ++j)
                acc[i][j] = __builtin_amdgcn_mfma_f32_16x16x32_bf16(afr, bfr[j], acc[i][j], 0, 0, 0);
        }
    }

    #pragma unroll
    for (int j = 0; j < 4; ++j) {
        int col = (int)bc + wc + j * 16 + l15;
        float bv = bias0[col];
        if (bias1) bv += bias1[col];
        #pragma unroll
        for (int i = 0; i < 4; ++i) {
            int rowb = (int)br + wr + i * 16 + q * 4;
            if (mode == 2) {
                // rows rowb..rowb+3 share everything except rr (= b&3) -> one float4
                int t = rowb >> 6, b = rowb & 63;
                int bg = b >> 4, q2 = (b >> 2) & 3;
                int gt = col >> 8, wv_ = (col >> 6) & 3, jf = (col >> 4) & 3;
                int fi = gt * 4 + jf, lane2 = q2 * 16 + (col & 15);
                float4 o4;
                o4.x = acc[i][j][0] + bv; o4.y = acc[i][j][1] + bv;
                o4.z = acc[i][j][2] + bv; o4.w = acc[i][j][3] + bv;
                *(float4*)(outF + (((size_t)bg * 96 + t) * 4 + wv_) * 4096 + fi * 256 + lane2 * 4) = o4;
            } else {
                #pragma unroll
                for (int rr = 0; rr < 4; ++rr) {
                    int row = rowb + rr;
                    float v = acc[i][j][rr] + bv;
                    if (mode == 0) {
                        outB[(size_t)row * ldo + col] = (bf16_t)v;
                    } else {
                        int orow = (row & 63) * T_LEN + (row >> 6);
                        outF[(size_t)orow * ldo + col] = v;
                    }
                }
            }
        }
    }
}

// ---------------- sync-free batch-partitioned bidirectional LSTM layer ----------------
// grid: 8 blocks = dir(2) x batch-group(4). 256 threads = 4 waves, 1 wave/SIMD (high VGPR).
// Block owns batch rows b0..b0+15 and computes the FULL [16 x 1024] gate GEMM each step:
// no cross-block communication at all (batch rows are independent recurrences).
// Whh (512 KB, frag-packed) split: 48 frags/wave VGPR-resident + 34 frags/wave LDS-resident
// + 46 frags/wave streamed from L2 each step through a 12-deep rolling register window.
// Wave w owns hidden cols j in [w*64, w*64+64): all 4 gates for those j -> h computed locally.
// h exchanged across waves via LDS hband (next step's A operand needs all 256 hidden cols).
#define RV 48
#define RL 34
#define SFRAG0 (RV + RL)       // 82
#define RS (128 - SFRAG0)      // 46 streamed frags per wave
#define SW 12                  // streamed in-flight window (regs)

__device__ __forceinline__ float sig_f(float x) {
    return 1.0f / (1.0f + __expf(-x));
}
__device__ __forceinline__ float tanh_f(float x) {
    float ax = fabsf(x);
    float e = __expf(-2.0f * ax);
    float t = (1.0f - e) / (1.0f + e);
    return copysignf(t, x);
}

__global__ __launch_bounds__(256, 1) void lstm_batch_kernel(
    const float* __restrict__ xg2f, const float* __restrict__ xg2b,   // [4 bg][96 t][4 w][4096] f32
    const bf16_t* __restrict__ wpkf, const bf16_t* __restrict__ wpkb, // [4 w][128 id][64 lane][8] bf16
    bf16_t* __restrict__ hall)                                        // [96 t][64 b][512] bf16
{
    __shared__ bf16_t wlds[4 * RL * 512];   // 136 KB: [w][j][lane*8]
    __shared__ bf16_t hband[16 * 264];      // 8.25 KB: h_prev [b_loc][j] pitch 264

    const int tid = threadIdx.x;
    const int dir = blockIdx.x >> 2, bg = blockIdx.x & 3;
    const int w = tid >> 6, lane = tid & 63, q = lane >> 4, l15 = lane & 15;
    const int b0 = bg * 16;

    const float* xgw = (dir ? xg2b : xg2f) + (size_t)bg * 96 * 16384 + w * 4096 + lane * 4;
    const bf16_t* wp = (dir ? wpkb : wpkf) + (size_t)w * 65536 + lane * 8;

    // one-time: VGPR-resident weight frags
    bf16x8 wv[RV];
    #pragma unroll
    for (int i = 0; i < RV; ++i)
        wv[i] = *(const bf16x8*)(wp + i * 512);
    // one-time: LDS-resident weight frags (wave-private region, no barrier needed)
    #pragma unroll
    for (int j = 0; j < RL; ++j) {
        bf16x8 v = *(const bf16x8*)(wp + (RV + j) * 512);
        *(bf16x8*)(wlds + ((w * RL + j) << 9) + lane * 8) = v;
    }

    float cst[16];
    #pragma unroll
    for (int i = 0; i < 16; ++i) cst[i] = 0.f;

    bf16x8 sb[SW];   // streamed window; filled at end of previous step's MFMA phase
    // prologue for s=0's successor is issued below in the s=0 iteration

    for (int s = 0; s < 96; ++s) {
        const int t = dir ? (95 - s) : s;
        const float* xgt = xgw + (size_t)t * 16384;
        // xg for this step: 16 coalesced float4 loads, consumed at gates
        f32x4 xgr[16];
        #pragma unroll
        for (int fi = 0; fi < 16; ++fi)
            xgr[fi] = *(const f32x4*)(xgt + fi * 256);

        // barrier(1): previous step's hband writes visible (LDS only -> lgkmcnt, skip vmcnt drain)
        asm volatile("s_waitcnt lgkmcnt(0)\ns_barrier" ::: "memory");

        f32x4 acc[16] = {};
        if (s > 0) {
            #pragma unroll
            for (int kq = 0; kq < 8; ++kq) {
                bf16x8 af = *(const bf16x8*)(hband + l15 * 264 + kq * 32 + q * 8);
                #pragma unroll
                for (int fi = 0; fi < 16; ++fi) {
                    const int id = kq * 16 + fi;
                    bf16x8 bw;
                    if (id < RV) {
                        bw = wv[id];
                    } else if (id < SFRAG0) {
                        bw = *(const bf16x8*)(wlds + ((w * RL + (id - RV)) << 9) + lane * 8);
                    } else {
                        const int si = id - SFRAG0;
                        bw = sb[si % SW];
                        if (si + SW < RS)
                            sb[si % SW] = *(const bf16x8*)(wp + (id + SW) * 512);
                    }
                    acc[fi] = __builtin_amdgcn_mfma_f32_16x16x32_bf16(af, bw, acc[fi], 0, 0, 0);
                }
            }
        }
        // prefetch next step's streamed prologue now (overlaps gates VALU below)
        if (s + 1 < 96) {
            #pragma unroll
            for (int i = 0; i < SW; ++i)
                sb[i] = *(const bf16x8*)(wp + (SFRAG0 + i) * 512);
        }
        // gates + state update
        float hv[16];
        #pragma unroll
        for (int jf = 0; jf < 4; ++jf) {
            #pragma unroll
            for (int rr = 0; rr < 4; ++rr) {
                const int ci = jf * 4 + rr;
                float ai  = acc[jf][rr]      + xgr[jf][rr];
                float afv = acc[4 + jf][rr]  + xgr[4 + jf][rr];
                float ag  = acc[8 + jf][rr]  + xgr[8 + jf][rr];
                float ao  = acc[12 + jf][rr] + xgr[12 + jf][rr];
                float iv = sig_f(ai), fv = sig_f(afv);
                float gv = tanh_f(ag), ov = sig_f(ao);
                cst[ci] = (s == 0) ? (iv * gv) : (fv * cst[ci] + iv * gv);
                hv[ci] = ov * tanh_f(cst[ci]);
            }
        }
        // barrier(2): all waves done reading hband (A-frags) before overwrite
        __syncthreads();
        #pragma unroll
        for (int jf = 0; jf < 4; ++jf) {
            #pragma unroll
            for (int rr = 0; rr < 4; ++rr) {
                bf16_t hb = (bf16_t)hv[jf * 4 + rr];
                hband[(q * 4 + rr) * 264 + w * 64 + jf * 16 + l15] = hb;
                hall[(((size_t)t * 64 + b0 + q * 4 + rr) << 9) + dir * 256 + w * 64 + jf * 16 + l15] = hb;
            }
        }
    }
}

// ---------------- hall (layer1) -> fp32 output columns ----------------
__global__ __launch_bounds__(256) void out_expand_kernel(
    const bf16_t* __restrict__ hall, float* __restrict__ out)  // out pre-offset to col 1024
{
    const int t = blockIdx.x;
    const int b = threadIdx.x >> 2, seg = threadIdx.x & 3;
    const bf16_t* src = hall + (((size_t)t * 64 + b) << 9) + seg * 128;
    float* dst = out + ((size_t)b * 96 + t) * 1536 + seg * 128;
    #pragma unroll
    for (int i = 0; i < 16; ++i) {
        bf16x8 v = ((const bf16x8*)src)[i];
        float4 lo, hi;
        lo.x = (float)v[0]; lo.y = (float)v[1]; lo.z = (float)v[2]; lo.w = (float)v[3];
        hi.x = (float)v[4]; hi.y = (float)v[5]; hi.z = (float)v[6]; hi.w = (float)v[7];
        ((float4*)dst)[2 * i]     = lo;
        ((float4*)dst)[2 * i + 1] = hi;
    }
}

// ---------------- host ----------------
extern "C" void kernel_launch(void* const* d_in, const int* in_sizes, int n_in,
                              void* d_out, int out_size, void* d_ws, size_t ws_size,
                              hipStream_t stream)
{
    const float* r1 = (const float*)d_in[0];
    const float* r2 = (const float*)d_in[1];
    const float* r3 = (const float*)d_in[2];
    const float* r4 = (const float*)d_in[3];
    const float* U_a = (const float*)d_in[4];
    const float* U_v = (const float*)d_in[5];
    const float* W_a = (const float*)d_in[7];
    const float* b_a = (const float*)d_in[8];
    const float* W_v = (const float*)d_in[9];
    const float* b_v = (const float*)d_in[10];
    const float* W_l = (const float*)d_in[11];
    const float* b_l = (const float*)d_in[12];
    const float* Wih0f = (const float*)d_in[13];
    const float* Whh0f = (const float*)d_in[14];
    const float* bih0f = (const float*)d_in[15];
    const float* bhh0f = (const float*)d_in[16];
    const float* Wih0b = (const float*)d_in[17];
    const float* Whh0b = (const float*)d_in[18];
    const float* bih0b = (const float*)d_in[19];
    const float* bhh0b = (const float*)d_in[20];
    const float* Wih1f = (const float*)d_in[21];
    const float* Whh1f = (const float*)d_in[22];
    const float* bih1f = (const float*)d_in[23];
    const float* bhh1f = (const float*)d_in[24];
    const float* Wih1b = (const float*)d_in[25];
    const float* Whh1b = (const float*)d_in[26];
    const float* bih1b = (const float*)d_in[27];
    const float* bhh1b = (const float*)d_in[28];
    float* out = (float*)d_out;

    char* wsb = (char*)d_ws;
    size_t off = 0;
    auto alloc = [&](size_t bytes) -> void* {
        void* p = wsb + off;
        off = (off + bytes + 255) & ~(size_t)255;
        return p;
    };
    float*  stats   = (float*)alloc(512 * sizeof(float));
    bf16_t* Ub      = (bf16_t*)alloc((size_t)NTB * 1024 * 2);
    bf16_t* Uab     = (bf16_t*)alloc((size_t)NTB * 128 * 2);
    bf16_t* Wab     = (bf16_t*)alloc((size_t)512 * 128 * 2);
    bf16_t* Uvb     = (bf16_t*)alloc((size_t)NTB * 512 * 2);
    bf16_t* Wvb     = (bf16_t*)alloc((size_t)512 * 512 * 2);
    bf16_t* Wlb     = (bf16_t*)alloc((size_t)512 * 1024 * 2);
    bf16_t* Wih0fb  = (bf16_t*)alloc((size_t)1024 * 512 * 2);
    bf16_t* Wih0bb  = (bf16_t*)alloc((size_t)1024 * 512 * 2);
    bf16_t* Wih1fb  = (bf16_t*)alloc((size_t)1024 * 512 * 2);
    bf16_t* Wih1bb  = (bf16_t*)alloc((size_t)1024 * 512 * 2);
    bf16_t* Ulb     = (bf16_t*)alloc((size_t)NTB * 512 * 2);
    float*  xgpf    = (float*)alloc((size_t)NTB * 1024 * 4);
    float*  xgpb    = (float*)alloc((size_t)NTB * 1024 * 4);
    bf16_t* wrb0f   = (bf16_t*)alloc((size_t)4 * 128 * 64 * 8 * 2);
    bf16_t* wrb0b   = (bf16_t*)alloc((size_t)4 * 128 * 64 * 8 * 2);
    bf16_t* wrb1f   = (bf16_t*)alloc((size_t)4 * 128 * 64 * 8 * 2);
    bf16_t* wrb1b   = (bf16_t*)alloc((size_t)4 * 128 * 64 * 8 * 2);
    bf16_t* hall0   = (bf16_t*)alloc((size_t)96 * 64 * 512 * 2);
    bf16_t* hall1   = (bf16_t*)alloc((size_t)96 * 64 * 512 * 2);

    // LN2 + U
    ln_stats_kernel<<<256, 256, 0, stream>>>(r1, r2, r3, r4, stats);
    compute_u_kernel<<<NTB * 1024 / 4 / 256, 256, 0, stream>>>(r1, r2, r3, r4, stats, Ub);

    // bf16 staging casts
    cast_pad_kernel<<<NTB * 128 / 256, 256, 0, stream>>>(U_a, Uab, NTB, 100, 128);
    cast_pad_kernel<<<512 * 128 / 256, 256, 0, stream>>>(W_a, Wab, 512, 100, 128);
    cast_pad_kernel<<<NTB * 512 / 256, 256, 0, stream>>>(U_v, Uvb, NTB, 512, 512);
    cast_pad_kernel<<<512 * 512 / 256, 256, 0, stream>>>(W_v, Wvb, 512, 512, 512);
    cast_pad_kernel<<<512 * 1024 / 256, 256, 0, stream>>>(W_l, Wlb, 512, 1024, 1024);
    cast_pad_kernel<<<1024 * 512 / 256, 256, 0, stream>>>(Wih0f, Wih0fb, 1024, 512, 512);
    cast_pad_kernel<<<1024 * 512 / 256, 256, 0, stream>>>(Wih0b, Wih0bb, 1024, 512, 512);
    cast_pad_kernel<<<1024 * 512 / 256, 256, 0, stream>>>(Wih1f, Wih1fb, 1024, 512, 512);
    cast_pad_kernel<<<1024 * 512 / 256, 256, 0, stream>>>(Wih1b, Wih1bb, 1024, 512, 512);

    // Whh frag-lane-major repacks (one-time)
    wpk_pack_kernel<<<1024, 256, 0, stream>>>(Whh0f, wrb0f);
    wpk_pack_kernel<<<1024, 256, 0, stream>>>(Whh0b, wrb0b);
    wpk_pack_kernel<<<1024, 256, 0, stream>>>(Whh1f, wrb1f);
    wpk_pack_kernel<<<1024, 256, 0, stream>>>(Whh1b, wrb1b);

    // emotions_a -> out[:, 0:512] ; emotions_v -> out[:, 512:1024]  (mode 1: permuted rows)
    gemm_bt_kernel<<<dim3(4, 48), 256, 0, stream>>>(Uab, Wab, b_a, nullptr, 128, out, nullptr, 1536, 1);
    gemm_bt_kernel<<<dim3(4, 48), 256, 0, stream>>>(Uvb, Wvb, b_v, nullptr, 512, out + 512, nullptr, 1536, 1);
    // Ul (bf16)
    gemm_bt_kernel<<<dim3(4, 48), 256, 0, stream>>>(Ub, Wlb, b_l, nullptr, 1024, nullptr, Ulb, 512, 0);
    // layer0 input projections -> xg2 packed layout (mode 2)
    gemm_bt_kernel<<<dim3(8, 48), 256, 0, stream>>>(Ulb, Wih0fb, bih0f, bhh0f, 512, xgpf, nullptr, 0, 2);
    gemm_bt_kernel<<<dim3(8, 48), 256, 0, stream>>>(Ulb, Wih0bb, bih0b, bhh0b, 512, xgpb, nullptr, 0, 2);
    // layer0 recurrence (sync-free, batch-partitioned)
    lstm_batch_kernel<<<8, 256, 0, stream>>>(xgpf, xgpb, wrb0f, wrb0b, hall0);
    // layer1 input projections (A = hall0 == [6144][512] bf16)
    gemm_bt_kernel<<<dim3(8, 48), 256, 0, stream>>>(hall0, Wih1fb, bih1f, bhh1f, 512, xgpf, nullptr, 0, 2);
    gemm_bt_kernel<<<dim3(8, 48), 256, 0, stream>>>(hall0, Wih1bb, bih1b, bhh1b, 512, xgpb, nullptr, 0, 2);
    // layer1 recurrence
    lstm_batch_kernel<<<8, 256, 0, stream>>>(xgpf, xgpb, wrb1f, wrb1b, hall1);
    // final fp32 expand -> out[:, 1024:1536]
    out_expand_kernel<<<96, 256, 0, stream>>>(hall1, out + 1024);
}

// Round 3
// 1131.812 us; speedup vs baseline: 1.9487x; 1.9487x over previous
//
#include <hip/hip_runtime.h>
#include <hip/hip_bf16.h>
#include <cstddef>

typedef __bf16 bf16_t;
typedef __bf16 bf16x8 __attribute__((ext_vector_type(8)));
typedef __bf16 bf16x4 __attribute__((ext_vector_type(4)));
typedef float f32x4 __attribute__((ext_vector_type(4)));

#define T_LEN 96
#define BATCH 64
#define DM 1024
#define NTB 6144  // T*B

// ---------------- LN2 stats: per (tensor i, batch b) mean & inv-std over T*DM ----------------
__global__ __launch_bounds__(256) void ln_stats_kernel(
    const float* __restrict__ r1, const float* __restrict__ r2,
    const float* __restrict__ r3, const float* __restrict__ r4,
    float* __restrict__ stats)  // [4*64][2]
{
    const int i = blockIdx.x >> 6, b = blockIdx.x & 63;
    const float* r = (i == 0) ? r1 : (i == 1) ? r2 : (i == 2) ? r3 : r4;
    float s = 0.f, ss = 0.f;
    for (int t = 0; t < T_LEN; ++t) {
        float4 v = ((const float4*)(r + (size_t)(t * BATCH + b) * DM))[threadIdx.x];
        s  += v.x + v.y + v.z + v.w;
        ss += v.x * v.x + v.y * v.y + v.z * v.z + v.w * v.w;
    }
    __shared__ float sh[512];
    sh[threadIdx.x] = s; sh[256 + threadIdx.x] = ss;
    __syncthreads();
    for (int off = 128; off > 0; off >>= 1) {
        if (threadIdx.x < off) {
            sh[threadIdx.x] += sh[threadIdx.x + off];
            sh[256 + threadIdx.x] += sh[256 + threadIdx.x + off];
        }
        __syncthreads();
    }
    if (threadIdx.x == 0) {
        const float inv = 1.0f / (float)(T_LEN * DM);
        float mean = sh[0] * inv;
        float var  = sh[256] * inv - mean * mean;
        stats[blockIdx.x * 2 + 0] = mean;
        stats[blockIdx.x * 2 + 1] = rsqrtf(var + 1e-5f);
    }
}

// ---------------- U = mean of 4 normalized tensors, written as bf16 [NTB,1024] ----------------
__global__ __launch_bounds__(256) void compute_u_kernel(
    const float* __restrict__ r1, const float* __restrict__ r2,
    const float* __restrict__ r3, const float* __restrict__ r4,
    const float* __restrict__ stats, bf16_t* __restrict__ U)
{
    const int idx4 = blockIdx.x * 256 + threadIdx.x;   // over NTB*1024/4
    const int b = (idx4 >> 8) & 63;
    const float m0 = stats[(0 * 64 + b) * 2], s0 = stats[(0 * 64 + b) * 2 + 1];
    const float m1 = stats[(1 * 64 + b) * 2], s1 = stats[(1 * 64 + b) * 2 + 1];
    const float m2 = stats[(2 * 64 + b) * 2], s2 = stats[(2 * 64 + b) * 2 + 1];
    const float m3 = stats[(3 * 64 + b) * 2], s3 = stats[(3 * 64 + b) * 2 + 1];
    float4 a = ((const float4*)r1)[idx4];
    float4 c = ((const float4*)r2)[idx4];
    float4 d = ((const float4*)r3)[idx4];
    float4 e = ((const float4*)r4)[idx4];
    bf16x4 o;
    o[0] = (bf16_t)(0.25f * ((a.x - m0) * s0 + (c.x - m1) * s1 + (d.x - m2) * s2 + (e.x - m3) * s3));
    o[1] = (bf16_t)(0.25f * ((a.y - m0) * s0 + (c.y - m1) * s1 + (d.y - m2) * s2 + (e.y - m3) * s3));
    o[2] = (bf16_t)(0.25f * ((a.z - m0) * s0 + (c.z - m1) * s1 + (d.z - m2) * s2 + (e.z - m3) * s3));
    o[3] = (bf16_t)(0.25f * ((a.w - m0) * s0 + (c.w - m1) * s1 + (d.w - m2) * s2 + (e.w - m3) * s3));
    ((bf16x4*)U)[idx4] = o;
}

// ---------------- f32 -> bf16 cast with optional K padding ----------------
__global__ __launch_bounds__(256) void cast_pad_kernel(
    const float* __restrict__ src, bf16_t* __restrict__ dst,
    int rows, int K, int Kpad)
{
    int idx = blockIdx.x * 256 + threadIdx.x;
    if (idx >= rows * Kpad) return;
    int r = idx / Kpad;
    int k = idx - r * Kpad;
    float v = (k < K) ? src[(size_t)r * K + k] : 0.f;
    dst[idx] = (bf16_t)v;
}

// ---------------- Whh fp32 [1024][256] -> MFMA frag pack for lstm_batch_kernel ----------------
// dst: [wv(8)][fid(64)][lane(64)][e(8)] bf16, fid = jf*32 + gt*8 + kq.
// value = Whh[gt*256 + wv*32 + jf*16 + (lane&15)][kq*32 + (lane>>4)*8 + e]
__global__ __launch_bounds__(256) void wpk_pack_kernel(
    const float* __restrict__ whh, bf16_t* __restrict__ dst)
{
    int i = blockIdx.x * 256 + threadIdx.x;   // 8*64*64*8 = 262144
    int e = i & 7, lane = (i >> 3) & 63, fid = (i >> 9) & 63, wv = i >> 15;
    int kq = fid & 7, gt = (fid >> 3) & 3, jf = fid >> 5;
    int nrow = gt * 256 + wv * 32 + jf * 16 + (lane & 15);
    int k = kq * 32 + (lane >> 4) * 8 + e;
    dst[i] = (bf16_t)whh[nrow * 256 + k];
}

// ---------------- bf16 MFMA GEMM: C[M,N] = A[M,K] @ W[N,K]^T + bias ----------------
// mode 0: outB bf16 row-major ldo.  mode 1: outF fp32, rows permuted (b*96+t), ldo.
// mode 2: outF fp32 in xg lane-major layout for lstm_batch_kernel:
//         [bg(4)][t(96)][wv(8)][jf(2)][gt(4)][lane(64)][rr(4)] f32
#define GLDP 40  // LDS row pitch in bf16 (32 + 8 pad)
__global__ __launch_bounds__(256) void gemm_bt_kernel(
    const bf16_t* __restrict__ A, const bf16_t* __restrict__ W,
    const float* __restrict__ bias0, const float* __restrict__ bias1,
    int K, float* __restrict__ outF, bf16_t* __restrict__ outB,
    int ldo, int mode)
{
    __shared__ bf16_t As[128 * GLDP];
    __shared__ bf16_t Bs[128 * GLDP];
    const int tid = threadIdx.x;
    const int lane = tid & 63;
    const int wid = tid >> 6;
    const int q = lane >> 4, l15 = lane & 15;
    const int wr = (wid >> 1) * 64, wc = (wid & 1) * 64;
    const size_t br = (size_t)blockIdx.y * 128;
    const size_t bc = (size_t)blockIdx.x * 128;

    const int r0 = tid >> 2;
    const int r1 = r0 + 64;
    const int k0 = (tid & 3) * 8;

    f32x4 acc[4][4] = {};

    for (int kt = 0; kt < K; kt += 32) {
        bf16x8 a0 = *(const bf16x8*)(A + (br + r0) * K + kt + k0);
        bf16x8 a1 = *(const bf16x8*)(A + (br + r1) * K + kt + k0);
        bf16x8 w0 = *(const bf16x8*)(W + (bc + r0) * K + kt + k0);
        bf16x8 w1 = *(const bf16x8*)(W + (bc + r1) * K + kt + k0);
        if (kt) __syncthreads();
        *(bf16x8*)(As + r0 * GLDP + k0) = a0;
        *(bf16x8*)(As + r1 * GLDP + k0) = a1;
        *(bf16x8*)(Bs + r0 * GLDP + k0) = w0;
        *(bf16x8*)(Bs + r1 * GLDP + k0) = w1;
        __syncthreads();
        bf16x8 bfr[4];
        #pragma unroll
        for (int j = 0; j < 4; ++j)
            bfr[j] = *(const bf16x8*)(Bs + (wc + j * 16 + l15) * GLDP + q * 8);
        #pragma unroll
        for (int i = 0; i < 4; ++i) {
            bf16x8 afr = *(const bf16x8*)(As + (wr + i * 16 + l15) * GLDP + q * 8);
            #pragma unroll
            for (int j = 0; j < 4; ++j)
                acc[i][j] = __builtin_amdgcn_mfma_f32_16x16x32_bf16(afr, bfr[j], acc[i][j], 0, 0, 0);
        }
    }

    #pragma unroll
    for (int j = 0; j < 4; ++j) {
        int col = (int)bc + wc + j * 16 + l15;
        float bv = bias0[col];
        if (bias1) bv += bias1[col];
        #pragma unroll
        for (int i = 0; i < 4; ++i) {
            int rowb = (int)br + wr + i * 16 + q * 4;
            if (mode == 2) {
                // rows rowb..rowb+3 differ only in rr -> one float4 store
                int t = rowb >> 6, b = rowb & 63;
                int bg = b >> 4, q2 = (b >> 2) & 3;
                int gt = col >> 8, hcol = col & 255;
                int wv2 = hcol >> 5, jf = (hcol >> 4) & 1, jj = col & 15;
                float4 o4;
                o4.x = acc[i][j][0] + bv; o4.y = acc[i][j][1] + bv;
                o4.z = acc[i][j][2] + bv; o4.w = acc[i][j][3] + bv;
                *(float4*)(outF + (((size_t)bg * 96 + t) * 16384)
                                 + wv2 * 2048 + jf * 1024 + gt * 256
                                 + (q2 * 16 + jj) * 4) = o4;
            } else {
                #pragma unroll
                for (int rr = 0; rr < 4; ++rr) {
                    int row = rowb + rr;
                    float v = acc[i][j][rr] + bv;
                    if (mode == 0) {
                        outB[(size_t)row * ldo + col] = (bf16_t)v;
                    } else {
                        int orow = (row & 63) * T_LEN + (row >> 6);
                        outF[(size_t)orow * ldo + col] = v;
                    }
                }
            }
        }
    }
}

// ---------------- sync-free batch-partitioned bidirectional LSTM layer ----------------
// grid: 8 blocks = dir(2) x batch-group(4 of 16 b). 512 threads = 8 waves = 2 waves/SIMD.
// Block owns 16 batch rows, computes the FULL [16 x 1024] gate GEMM per step: NO cross-block sync.
// Whh (512 KB/dir, frag-packed, 64 frags/wave): 38 frags VGPR-resident + 18 LDS-resident (144 KB,
// loaded once) + 8 streamed from L2 each step via a short-lived 32-reg window (issued mid-step,
// ~500cyc cover; weights stay L2-hot). Step split into two jf-phases (16 cols each) to halve
// acc/xg live ranges and fit 2 waves/SIMD (<=256 VGPR).
// hband [16 b][264] single buffer, 2 intra-CU barriers/step.
#define HB_P 264

__device__ __forceinline__ float sig_f(float x) {
    return __builtin_amdgcn_rcpf(1.0f + __expf(-x));
}
__device__ __forceinline__ float tanh_f(float x) {
    return 1.0f - 2.0f * __builtin_amdgcn_rcpf(1.0f + __expf(2.0f * x));
}

__global__ __launch_bounds__(512, 2) void lstm_batch_kernel(
    const float* __restrict__ xg2f, const float* __restrict__ xg2b,   // [4 bg][96 t][16384] f32
    const bf16_t* __restrict__ wpkf, const bf16_t* __restrict__ wpkb, // [8 wv][64 fid][64][8] bf16
    bf16_t* __restrict__ hall)                                        // [96 t][64 b][512] bf16
{
    __shared__ bf16_t wlds[8 * 18 * 512];   // 144 KB
    __shared__ bf16_t hband[16 * HB_P];     // 8.25 KB

    const int tid = threadIdx.x;
    const int dir = blockIdx.x >> 2, bg = blockIdx.x & 3;
    const int wv = tid >> 6, lane = tid & 63, q = lane >> 4, l15 = lane & 15;
    const int b0 = bg * 16;

    const float* xgw = (dir ? xg2b : xg2f) + (size_t)bg * 96 * 16384 + wv * 2048 + lane * 4;
    const bf16_t* wp = (dir ? wpkb : wpkf) + ((size_t)wv * 4096 + lane) * 8;

    // one-time: VGPR-resident frags (fid 0..37; phase A = fid 0..31 all here)
    bf16x8 wreg[38];
    #pragma unroll
    for (int f = 0; f < 38; ++f)
        wreg[f] = *(const bf16x8*)(wp + (size_t)f * 512);
    // one-time: LDS-resident frags (fid 38..55), wave-private region
    #pragma unroll
    for (int f = 0; f < 18; ++f) {
        bf16x8 v = *(const bf16x8*)(wp + (size_t)(38 + f) * 512);
        *(bf16x8*)(wlds + (((wv * 18 + f) << 9) + lane * 8)) = v;
    }

    float cstA[4] = {0.f, 0.f, 0.f, 0.f};
    float cstB[4] = {0.f, 0.f, 0.f, 0.f};

    for (int s = 0; s < 96; ++s) {
        const int t = dir ? (95 - s) : s;
        const float* xgt = xgw + (size_t)t * 16384;
        // xg phase A (jf=0): 4 coalesced float4
        f32x4 xga[4];
        #pragma unroll
        for (int gt = 0; gt < 4; ++gt) xga[gt] = *(const f32x4*)(xgt + gt * 256);

        // phase A MFMA (cols wv*32 .. +16): weights all VGPR-resident
        f32x4 acc[4] = {};
        if (s > 0) {
            #pragma unroll
            for (int kq = 0; kq < 8; ++kq) {
                bf16x8 af = *(const bf16x8*)(hband + l15 * HB_P + kq * 32 + q * 8);
                #pragma unroll
                for (int gt = 0; gt < 4; ++gt)
                    acc[gt] = __builtin_amdgcn_mfma_f32_16x16x32_bf16(af, wreg[gt * 8 + kq], acc[gt], 0, 0, 0);
            }
        }
        // streamed frags for phase B gt=3 (fid 56..63): issue now, used ~500cyc later
        bf16x8 sw[8];
        #pragma unroll
        for (int i = 0; i < 8; ++i)
            sw[i] = *(const bf16x8*)(wp + (size_t)(56 + i) * 512);
        // xg phase B
        f32x4 xgb[4];
        #pragma unroll
        for (int gt = 0; gt < 4; ++gt) xgb[gt] = *(const f32x4*)(xgt + 1024 + gt * 256);

        // gates A
        float hvA[4], hvB[4];
        #pragma unroll
        for (int rr = 0; rr < 4; ++rr) {
            float ai  = acc[0][rr] + xga[0][rr];
            float af_ = acc[1][rr] + xga[1][rr];
            float ag  = acc[2][rr] + xga[2][rr];
            float ao  = acc[3][rr] + xga[3][rr];
            float iv = sig_f(ai), fv = sig_f(af_);
            float gv = tanh_f(ag), ov = sig_f(ao);
            cstA[rr] = (s == 0) ? (iv * gv) : (fv * cstA[rr] + iv * gv);
            hvA[rr] = ov * tanh_f(cstA[rr]);
        }

        // phase B MFMA (cols wv*32+16 .. +32): fid = 32 + gt*8 + kq
        f32x4 accB[4] = {};
        if (s > 0) {
            #pragma unroll
            for (int kq = 0; kq < 8; ++kq) {
                bf16x8 af = *(const bf16x8*)(hband + l15 * HB_P + kq * 32 + q * 8);
                #pragma unroll
                for (int gt = 0; gt < 4; ++gt) {
                    const int fid = 32 + gt * 8 + kq;
                    bf16x8 bw;
                    if (fid < 38)       bw = wreg[fid];
                    else if (fid < 56)  bw = *(const bf16x8*)(wlds + (((wv * 18 + (fid - 38)) << 9) + lane * 8));
                    else                bw = sw[fid - 56];
                    accB[gt] = __builtin_amdgcn_mfma_f32_16x16x32_bf16(af, bw, accB[gt], 0, 0, 0);
                }
            }
        }
        // gates B
        #pragma unroll
        for (int rr = 0; rr < 4; ++rr) {
            float ai  = accB[0][rr] + xgb[0][rr];
            float af_ = accB[1][rr] + xgb[1][rr];
            float ag  = accB[2][rr] + xgb[2][rr];
            float ao  = accB[3][rr] + xgb[3][rr];
            float iv = sig_f(ai), fv = sig_f(af_);
            float gv = tanh_f(ag), ov = sig_f(ao);
            cstB[rr] = (s == 0) ? (iv * gv) : (fv * cstB[rr] + iv * gv);
            hvB[rr] = ov * tanh_f(cstB[rr]);
        }

        __syncthreads();   // all hband reads of step s done
        #pragma unroll
        for (int rr = 0; rr < 4; ++rr) {
            hband[(q * 4 + rr) * HB_P + wv * 32 + l15]      = (bf16_t)hvA[rr];
            hband[(q * 4 + rr) * HB_P + wv * 32 + 16 + l15] = (bf16_t)hvB[rr];
        }
        __syncthreads();   // hband writes visible
        // cooperative hall store: 512 thr x 16 B = 8 KB, coalesced
        {
            const int bl = tid >> 5, c8 = (tid & 31) * 8;
            bf16x8 v = *(const bf16x8*)(hband + bl * HB_P + c8);
            *(bf16x8*)(hall + (((size_t)t * 64 + b0 + bl) << 9) + dir * 256 + c8) = v;
        }
    }
}

// ---------------- hall (layer1) -> fp32 output columns ----------------
__global__ __launch_bounds__(256) void out_expand_kernel(
    const bf16_t* __restrict__ hall, float* __restrict__ out)  // out pre-offset to col 1024
{
    const int t = blockIdx.x;
    const int b = threadIdx.x >> 2, seg = threadIdx.x & 3;
    const bf16_t* src = hall + (((size_t)t * 64 + b) << 9) + seg * 128;
    float* dst = out + ((size_t)b * 96 + t) * 1536 + seg * 128;
    #pragma unroll
    for (int i = 0; i < 16; ++i) {
        bf16x8 v = ((const bf16x8*)src)[i];
        float4 lo, hi;
        lo.x = (float)v[0]; lo.y = (float)v[1]; lo.z = (float)v[2]; lo.w = (float)v[3];
        hi.x = (float)v[4]; hi.y = (float)v[5]; hi.z = (float)v[6]; hi.w = (float)v[7];
        ((float4*)dst)[2 * i]     = lo;
        ((float4*)dst)[2 * i + 1] = hi;
    }
}

// ---------------- host ----------------
extern "C" void kernel_launch(void* const* d_in, const int* in_sizes, int n_in,
                              void* d_out, int out_size, void* d_ws, size_t ws_size,
                              hipStream_t stream)
{
    const float* r1 = (const float*)d_in[0];
    const float* r2 = (const float*)d_in[1];
    const float* r3 = (const float*)d_in[2];
    const float* r4 = (const float*)d_in[3];
    const float* U_a = (const float*)d_in[4];
    const float* U_v = (const float*)d_in[5];
    const float* W_a = (const float*)d_in[7];
    const float* b_a = (const float*)d_in[8];
    const float* W_v = (const float*)d_in[9];
    const float* b_v = (const float*)d_in[10];
    const float* W_l = (const float*)d_in[11];
    const float* b_l = (const float*)d_in[12];
    const float* Wih0f = (const float*)d_in[13];
    const float* Whh0f = (const float*)d_in[14];
    const float* bih0f = (const float*)d_in[15];
    const float* bhh0f = (const float*)d_in[16];
    const float* Wih0b = (const float*)d_in[17];
    const float* Whh0b = (const float*)d_in[18];
    const float* bih0b = (const float*)d_in[19];
    const float* bhh0b = (const float*)d_in[20];
    const float* Wih1f = (const float*)d_in[21];
    const float* Whh1f = (const float*)d_in[22];
    const float* bih1f = (const float*)d_in[23];
    const float* bhh1f = (const float*)d_in[24];
    const float* Wih1b = (const float*)d_in[25];
    const float* Whh1b = (const float*)d_in[26];
    const float* bih1b = (const float*)d_in[27];
    const float* bhh1b = (const float*)d_in[28];
    float* out = (float*)d_out;

    char* wsb = (char*)d_ws;
    size_t off = 0;
    auto alloc = [&](size_t bytes) -> void* {
        void* p = wsb + off;
        off = (off + bytes + 255) & ~(size_t)255;
        return p;
    };
    float*  stats   = (float*)alloc(512 * sizeof(float));
    bf16_t* Ub      = (bf16_t*)alloc((size_t)NTB * 1024 * 2);
    bf16_t* Uab     = (bf16_t*)alloc((size_t)NTB * 128 * 2);
    bf16_t* Wab     = (bf16_t*)alloc((size_t)512 * 128 * 2);
    bf16_t* Uvb     = (bf16_t*)alloc((size_t)NTB * 512 * 2);
    bf16_t* Wvb     = (bf16_t*)alloc((size_t)512 * 512 * 2);
    bf16_t* Wlb     = (bf16_t*)alloc((size_t)512 * 1024 * 2);
    bf16_t* Wih0fb  = (bf16_t*)alloc((size_t)1024 * 512 * 2);
    bf16_t* Wih0bb  = (bf16_t*)alloc((size_t)1024 * 512 * 2);
    bf16_t* Wih1fb  = (bf16_t*)alloc((size_t)1024 * 512 * 2);
    bf16_t* Wih1bb  = (bf16_t*)alloc((size_t)1024 * 512 * 2);
    bf16_t* Ulb     = (bf16_t*)alloc((size_t)NTB * 512 * 2);
    float*  xgpf    = (float*)alloc((size_t)NTB * 1024 * 4);
    float*  xgpb    = (float*)alloc((size_t)NTB * 1024 * 4);
    bf16_t* wrb0f   = (bf16_t*)alloc((size_t)8 * 64 * 64 * 8 * 2);
    bf16_t* wrb0b   = (bf16_t*)alloc((size_t)8 * 64 * 64 * 8 * 2);
    bf16_t* wrb1f   = (bf16_t*)alloc((size_t)8 * 64 * 64 * 8 * 2);
    bf16_t* wrb1b   = (bf16_t*)alloc((size_t)8 * 64 * 64 * 8 * 2);
    bf16_t* hall0   = (bf16_t*)alloc((size_t)96 * 64 * 512 * 2);
    bf16_t* hall1   = (bf16_t*)alloc((size_t)96 * 64 * 512 * 2);

    // LN2 + U
    ln_stats_kernel<<<256, 256, 0, stream>>>(r1, r2, r3, r4, stats);
    compute_u_kernel<<<NTB * 1024 / 4 / 256, 256, 0, stream>>>(r1, r2, r3, r4, stats, Ub);

    // bf16 staging casts
    cast_pad_kernel<<<NTB * 128 / 256, 256, 0, stream>>>(U_a, Uab, NTB, 100, 128);
    cast_pad_kernel<<<512 * 128 / 256, 256, 0, stream>>>(W_a, Wab, 512, 100, 128);
    cast_pad_kernel<<<NTB * 512 / 256, 256, 0, stream>>>(U_v, Uvb, NTB, 512, 512);
    cast_pad_kernel<<<512 * 512 / 256, 256, 0, stream>>>(W_v, Wvb, 512, 512, 512);
    cast_pad_kernel<<<512 * 1024 / 256, 256, 0, stream>>>(W_l, Wlb, 512, 1024, 1024);
    cast_pad_kernel<<<1024 * 512 / 256, 256, 0, stream>>>(Wih0f, Wih0fb, 1024, 512, 512);
    cast_pad_kernel<<<1024 * 512 / 256, 256, 0, stream>>>(Wih0b, Wih0bb, 1024, 512, 512);
    cast_pad_kernel<<<1024 * 512 / 256, 256, 0, stream>>>(Wih1f, Wih1fb, 1024, 512, 512);
    cast_pad_kernel<<<1024 * 512 / 256, 256, 0, stream>>>(Wih1b, Wih1bb, 1024, 512, 512);

    // Whh frag repacks (one-time)
    wpk_pack_kernel<<<1024, 256, 0, stream>>>(Whh0f, wrb0f);
    wpk_pack_kernel<<<1024, 256, 0, stream>>>(Whh0b, wrb0b);
    wpk_pack_kernel<<<1024, 256, 0, stream>>>(Whh1f, wrb1f);
    wpk_pack_kernel<<<1024, 256, 0, stream>>>(Whh1b, wrb1b);

    // emotions_a -> out[:, 0:512] ; emotions_v -> out[:, 512:1024]  (mode 1: permuted rows)
    gemm_bt_kernel<<<dim3(4, 48), 256, 0, stream>>>(Uab, Wab, b_a, nullptr, 128, out, nullptr, 1536, 1);
    gemm_bt_kernel<<<dim3(4, 48), 256, 0, stream>>>(Uvb, Wvb, b_v, nullptr, 512, out + 512, nullptr, 1536, 1);
    // Ul (bf16)
    gemm_bt_kernel<<<dim3(4, 48), 256, 0, stream>>>(Ub, Wlb, b_l, nullptr, 1024, nullptr, Ulb, 512, 0);
    // layer0 input projections -> xg packed layout (mode 2)
    gemm_bt_kernel<<<dim3(8, 48), 256, 0, stream>>>(Ulb, Wih0fb, bih0f, bhh0f, 512, xgpf, nullptr, 0, 2);
    gemm_bt_kernel<<<dim3(8, 48), 256, 0, stream>>>(Ulb, Wih0bb, bih0b, bhh0b, 512, xgpb, nullptr, 0, 2);
    // layer0 recurrence (sync-free, batch-partitioned)
    lstm_batch_kernel<<<8, 512, 0, stream>>>(xgpf, xgpb, wrb0f, wrb0b, hall0);
    // layer1 input projections (A = hall0 == [6144][512] bf16)
    gemm_bt_kernel<<<dim3(8, 48), 256, 0, stream>>>(hall0, Wih1fb, bih1f, bhh1f, 512, xgpf, nullptr, 0, 2);
    gemm_bt_kernel<<<dim3(8, 48), 256, 0, stream>>>(hall0, Wih1bb, bih1b, bhh1b, 512, xgpb, nullptr, 0, 2);
    // layer1 recurrence
    lstm_batch_kernel<<<8, 512, 0, stream>>>(xgpf, xgpb, wrb1f, wrb1b, hall1);
    // final fp32 expand -> out[:, 1024:1536]
    out_expand_kernel<<<96, 256, 0, stream>>>(hall1, out + 1024);
}